// Round 14
// baseline (173.880 us; speedup 1.0000x reference)
//
#include <hip/hip_runtime.h>
#include <math.h>

#define NBINS 257
#define NMEL 80
#define MEL_FLOOR 1.192092955078125e-07f

constexpr int B = 16;
constexpr int T = 480000;
constexpr int F = 1 + (T - 400) / 160;   // 2998
constexpr int MT = 32;                    // frames per block
constexpr int BPB = (F + MT - 1) / MT;    // 94 blocks per batch
constexpr int AP = 426;                   // A LDS pitch in f16 (213 dwords, odd)
constexpr int PP = 265;                   // P LDS pitch (f32)
constexpr int NBLK = B * BPB;             // 1504

// ws float offsets
#define WS_BH    0         // f16[13][16][64][8] = 106496 f16 = 53248 floats
#define WS_BL    53248     // f16 lo
#define WS_K0    106496    // int[80]
#define WS_LEN   106576    // int[80]
#define WS_WGT   106656    // float[32*80]
#define WS_PART  109216    // float[1504][2][80] = 240640
#define WS_STAT  349856    // float[16][2][80]

typedef _Float16 f16x8 __attribute__((ext_vector_type(8)));
typedef float f32x4 __attribute__((ext_vector_type(4)));
typedef int i32x4 __attribute__((ext_vector_type(4)));

// negate odd-k elements of an A fragment: packed layout has odd k in high f16 of each dword
__device__ __forceinline__ f16x8 flip_odd(f16x8 v) {
    i32x4 u;
    __builtin_memcpy(&u, &v, 16);
    const i32x4 SGN = {(int)0x80000000, (int)0x80000000, (int)0x80000000, (int)0x80000000};
    u ^= SGN;
    f16x8 r;
    __builtin_memcpy(&r, &u, 16);
    return r;
}

// ---------------- Setup: DFT tables (blocks 0..51) + mel tables (block 52) ----------------
__global__ __launch_bounds__(256) void setup_kernel(
    const float* __restrict__ fil, float* __restrict__ ws)
{
    const int t = threadIdx.x;
    if (blockIdx.x < 52) {
        const int unit = blockIdx.x * 4 + (t >> 6);  // 0..207 = ks*16 + n16
        const int l = t & 63;
        const int n = (unit & 15) * 16 + (l & 15);   // col 0..255
        const int bin = n >> 1;                      // 0..127
        const int kbase = (unit >> 4) * 32 + (l >> 4) * 8;
        f16x8 vh, vl;
        #pragma unroll
        for (int j = 0; j < 8; ++j) {
            int k = kbase + j;
            float val = 0.0f;
            if (k < 400) {
                int kb = (k * bin) & 511;            // exact mod-512 reduction
                float ang = 6.283185307179586f * (float)kb * (1.0f / 512.0f);
                float s, c;
                sincosf(ang, &s, &c);
                val = (n & 1) ? s : c;
            }
            _Float16 h = (_Float16)val;
            float r = val - (float)h;
            vh[j] = h;
            vl[j] = (_Float16)r;
        }
        ((f16x8*)(ws + WS_BH))[unit * 64 + l] = vh;
        ((f16x8*)(ws + WS_BL))[unit * 64 + l] = vl;
        return;
    }
    __shared__ int sh_k0[3][NMEL], sh_k1[3][NMEL];
    __shared__ int sh_K0[NMEL], sh_LEN[NMEL];
    if (t < 240) {
        int m = t % NMEL, r = t / NMEL;
        int kb = r * 86, ke = (kb + 86 < NBINS) ? (kb + 86) : NBINS;
        int k0 = -1, k1 = -1;
        for (int k = kb; k < ke; ++k) {
            if (fil[k * NMEL + m] > 0.0f) { if (k0 < 0) k0 = k; k1 = k; }
        }
        sh_k0[r][m] = k0; sh_k1[r][m] = k1;
    }
    __syncthreads();
    if (t < NMEL) {
        int k0 = -1, k1 = -1;
        for (int r = 0; r < 3; ++r) {
            int a = sh_k0[r][t], b1 = sh_k1[r][t];
            if (a >= 0) { if (k0 < 0) k0 = a; k1 = b1; }
        }
        int len = (k0 < 0) ? 0 : (k1 - k0 + 1);
        if (len > 32) len = 32;
        if (k0 < 0) k0 = 0;
        ((int*)ws)[WS_K0 + t] = k0;
        ((int*)ws)[WS_LEN + t] = len;
        sh_K0[t] = k0; sh_LEN[t] = len;
    }
    __syncthreads();
    for (int idx = t; idx < 32 * NMEL; idx += 256) {
        int j = idx / NMEL, m = idx - j * NMEL;
        ws[WS_WGT + idx] = (j < sh_LEN[m]) ? fil[(sh_K0[m] + j) * NMEL + m] : 0.0f;
    }
}

// ---------------- Main: 32 frames -> log-mel, half-spectrum GEMM + alt-sign rows ----------------
__global__ __launch_bounds__(512, 4) void gemm_logmel_kernel(
    const float* __restrict__ wav,
    const float* __restrict__ win,
    float* __restrict__ ws,
    float* __restrict__ mel_out)
{
    __shared__ __attribute__((aligned(16))) char lds[79104];
    _Float16* A_hi = (_Float16*)lds;                  // [32][426] f16 = 27264 B
    _Float16* A_lo = (_Float16*)(lds + 27264);        // 27264 B
    float* P_s    = (float*)lds;                      // [32][265] f32, aliases A (after K-loop)
    float* raw    = (float*)(lds + 54528);            // 5376 f32
    float* win_s  = (float*)(lds + 76032);            // 400 f32
    float* S16_s  = (float*)(lds + 77632);            // 336 f32 (later: X128 re/im, 64 f32)
    float* mean_s = (float*)(lds + 78976);            // 32 f32

    const int t = threadIdx.x;
    const int l = t & 63, w = t >> 6;
    const int lane15 = l & 15, lhi = l >> 4;
    const int bid = blockIdx.x;
    const int b = bid / BPB, blk = bid - b * BPB;
    const int f0 = blk * MT;
    const int nfr = (F - f0 < MT) ? (F - f0) : MT;
    const size_t s0 = (size_t)b * T + (size_t)f0 * 160;

    if (t < 400) win_s[t] = win[t];

    // ---- phase 1a: raw span -> LDS ----
    {
        const float4* src4 = (const float4*)(wav + s0);
        #pragma unroll
        for (int it = 0; it < 3; ++it) {
            int i4 = t + it * 512;
            if (i4 < 1344) {
                float4 v = make_float4(0.f, 0.f, 0.f, 0.f);
                if (s0 + 4 * (size_t)i4 + 3 < (size_t)B * T) v = src4[i4];
                ((float4*)raw)[i4] = v;
            }
        }
    }
    __syncthreads();

    // ---- phase 1b: chunk sums -> per-frame means ----
    if (t < 336) {
        float s = 0.0f;
        #pragma unroll
        for (int q = 0; q < 4; ++q) {
            float4 v = ((const float4*)raw)[4 * t + q];
            s += v.x + v.y + v.z + v.w;
        }
        S16_s[t] = s;
    }
    __syncthreads();
    if (t < MT) {
        float s = 0.0f;
        #pragma unroll
        for (int i = 0; i < 25; ++i) s += S16_s[10 * t + i];
        mean_s[t] = s * (1.0f / 400.0f);
    }
    __syncthreads();

    // ---- phase 1c: build A hi/lo (k 400..415 stored as zeros) ----
    {
        const int f = t >> 4, j = t & 15;
        const float m = mean_s[f];
        const int base = f * 160;
        const bool dead = (f >= nfr);
        int k = j * 26;
        float xm = (k == 0) ? raw[base] : raw[base + k - 1];
        #pragma unroll
        for (int it = 0; it < 13; ++it) {
            float a0 = 0.0f, a1 = 0.0f;
            if (!dead && k < 400) {
                float x0 = raw[base + k];
                float x1 = raw[base + k + 1];
                a0 = (x0 - 0.97f * xm - 0.03f * m) * win_s[k];
                if (k + 1 < 400)
                    a1 = (x1 - 0.97f * x0 - 0.03f * m) * win_s[k + 1];
                xm = x1;
            }
            _Float16 h0 = (_Float16)a0, h1 = (_Float16)a1;
            float r0 = a0 - (float)h0, r1 = a1 - (float)h1;
            _Float16 e0 = (_Float16)r0, e1 = (_Float16)r1;
            unsigned uh = ((unsigned)*(unsigned short*)&h1 << 16) | *(unsigned short*)&h0;
            unsigned ul = ((unsigned)*(unsigned short*)&e1 << 16) | *(unsigned short*)&e0;
            *(unsigned*)&A_hi[f * AP + k] = uh;
            *(unsigned*)&A_lo[f * AP + k] = ul;
            k += 2;
        }
    }
    __syncthreads();

    // ---- bin-128 pre-pass: X[128] = sum over k of a[k]*(-i)^k (re: k%4 0/2, im: 1/3) ----
    {
        const int f = t >> 4, c = t & 15;
        float s = 0.0f;
        #pragma unroll
        for (int j = 0; j < 25; ++j) {
            int k = c + 16 * j;
            s += (float)A_hi[f * AP + k] + (float)A_lo[f * AP + k];
        }
        int cm = c & 3;
        float re = (cm == 0) ? s : (cm == 2 ? -s : 0.0f);
        float im = (cm == 1) ? s : (cm == 3 ? -s : 0.0f);
        #pragma unroll
        for (int m2 = 8; m2 >= 1; m2 >>= 1) {
            re += __shfl_xor(re, m2);
            im += __shfl_xor(im, m2);
        }
        if (c == 0) { S16_s[f] = re; S16_s[32 + f] = im; }
    }

    // ---- phase 2: K-loop. N=256 (bins 0..127); alt rows (sign-flipped A) give bins 129..255 ----
    f32x4 acc[4][2] = {};
    const _Float16* Ah = A_hi + lane15 * AP + lhi * 8;
    const _Float16* Al = A_lo + lane15 * AP + lhi * 8;
    const f16x8* bh = (const f16x8*)(ws + WS_BH);
    const f16x8* bl = (const f16x8*)(ws + WS_BL);

    #pragma unroll
    for (int ks = 0; ks < 13; ++ks) {
        f16x8 ah0 = *(const f16x8*)(Ah + ks * 32);
        f16x8 ah1 = *(const f16x8*)(Ah + 16 * AP + ks * 32);
        f16x8 al0 = *(const f16x8*)(Al + ks * 32);
        f16x8 al1 = *(const f16x8*)(Al + 16 * AP + ks * 32);
        f16x8 gh0 = flip_odd(ah0), gh1 = flip_odd(ah1);
        f16x8 gl0 = flip_odd(al0), gl1 = flip_odd(al1);
        #pragma unroll
        for (int gi = 0; gi < 2; ++gi) {
            const int bidx = (ks * 16 + (w * 2 + gi)) * 64 + l;
            f16x8 bfh = bh[bidx];
            f16x8 bfl = bl[bidx];
            acc[0][gi] = __builtin_amdgcn_mfma_f32_16x16x32_f16(ah0, bfh, acc[0][gi], 0, 0, 0);
            acc[0][gi] = __builtin_amdgcn_mfma_f32_16x16x32_f16(ah0, bfl, acc[0][gi], 0, 0, 0);
            acc[0][gi] = __builtin_amdgcn_mfma_f32_16x16x32_f16(al0, bfh, acc[0][gi], 0, 0, 0);
            acc[1][gi] = __builtin_amdgcn_mfma_f32_16x16x32_f16(ah1, bfh, acc[1][gi], 0, 0, 0);
            acc[1][gi] = __builtin_amdgcn_mfma_f32_16x16x32_f16(ah1, bfl, acc[1][gi], 0, 0, 0);
            acc[1][gi] = __builtin_amdgcn_mfma_f32_16x16x32_f16(al1, bfh, acc[1][gi], 0, 0, 0);
            acc[2][gi] = __builtin_amdgcn_mfma_f32_16x16x32_f16(gh0, bfh, acc[2][gi], 0, 0, 0);
            acc[2][gi] = __builtin_amdgcn_mfma_f32_16x16x32_f16(gh0, bfl, acc[2][gi], 0, 0, 0);
            acc[2][gi] = __builtin_amdgcn_mfma_f32_16x16x32_f16(gl0, bfh, acc[2][gi], 0, 0, 0);
            acc[3][gi] = __builtin_amdgcn_mfma_f32_16x16x32_f16(gh1, bfh, acc[3][gi], 0, 0, 0);
            acc[3][gi] = __builtin_amdgcn_mfma_f32_16x16x32_f16(gh1, bfl, acc[3][gi], 0, 0, 0);
            acc[3][gi] = __builtin_amdgcn_mfma_f32_16x16x32_f16(gl1, bfh, acc[3][gi], 0, 0, 0);
        }
    }
    __syncthreads();   // all A reads done; P may overwrite A region

    // ---- phase 3a: power spectrum -> P_s ----
    #pragma unroll
    for (int rg = 0; rg < 4; ++rg) {
        const bool alt = (rg >= 2);
        const int fbase = (rg & 1) * 16;
        #pragma unroll
        for (int gi = 0; gi < 2; ++gi) {
            const int g = w * 2 + gi;
            #pragma unroll
            for (int r = 0; r < 4; ++r) {
                float v = acc[rg][gi][r];
                float p = v * v;
                p += __shfl_xor(p, 1);
                if ((l & 1) == 0) {
                    int bcol = (g * 16 + lane15) >> 1;           // 0..127
                    int bin = alt ? (256 - bcol) : bcol;
                    int fl_ = fbase + lhi * 4 + r;
                    if (!alt || bcol >= 1)
                        P_s[fl_ * PP + bin] = p;
                }
            }
        }
    }
    if (t < MT) {
        float re = S16_s[t], im = S16_s[32 + t];
        P_s[t * PP + 128] = re * re + im * im;
    }
    __syncthreads();

    // ---- phase 3b: sparse mel + log + fused stats partials ----
    {
        const int f = t & 31, g = t >> 5;
        const bool live = (f < nfr);
        const size_t outbase = (size_t)(b * F + f0 + f) * NMEL;
        const float* Pf = &P_s[f * PP];
        float* part = ws + WS_PART;
        #pragma unroll
        for (int i = 0; i < 5; ++i) {
            int mel = g * 5 + i;
            int k0 = ((const int*)ws)[WS_K0 + mel];
            int len = ((const int*)ws)[WS_LEN + mel];
            float a = 0.0f;
            for (int q = 0; q < len; ++q)
                a = fmaf(Pf[k0 + q], ws[WS_WGT + q * NMEL + mel], a);
            a = logf(fmaxf(a * 1073741824.0f, MEL_FLOOR));  // restore 32768^2
            if (live) mel_out[outbase + mel] = a;
            float v = live ? a : 0.0f;
            float v2 = v * v;
            #pragma unroll
            for (int m2 = 16; m2 >= 1; m2 >>= 1) {
                v += __shfl_xor(v, m2);
                v2 += __shfl_xor(v2, m2);
            }
            if (f == 0) {
                part[(bid * 2 + 0) * NMEL + mel] = v;
                part[(bid * 2 + 1) * NMEL + mel] = v2;
            }
        }
    }
}

// ---------------- finalize stats ----------------
__global__ __launch_bounds__(128) void stats_final_kernel(float* __restrict__ ws)
{
    const int b = blockIdx.x;
    const int m = threadIdx.x;
    if (m >= NMEL) return;
    const float* part = ws + WS_PART;
    double s = 0.0, s2 = 0.0;
    for (int c = 0; c < BPB; ++c) {
        int bid = b * BPB + c;
        s += (double)part[(bid * 2 + 0) * NMEL + m];
        s2 += (double)part[(bid * 2 + 1) * NMEL + m];
    }
    double mean = s / (double)F;
    double var = (s2 - s * s / (double)F) / (double)(F - 1);
    ws[WS_STAT + b * 2 * NMEL + m] = (float)mean;
    ws[WS_STAT + b * 2 * NMEL + NMEL + m] = (float)(1.0 / sqrt(var + 1e-7));
}

// ---------------- normalize (float4) + mask ----------------
__global__ __launch_bounds__(256) void norm_mask_kernel(
    float* __restrict__ out, const float* __restrict__ ws)
{
    const float* stat = ws + WS_STAT;
    const int total4 = (B * F * NMEL) / 4;
    const int stride = gridDim.x * blockDim.x;
    float4* out4 = (float4*)out;
    for (int e4 = blockIdx.x * blockDim.x + threadIdx.x; e4 < total4; e4 += stride) {
        int e = e4 * 4;
        int b = e / (F * NMEL);
        int m = e % NMEL;
        const float* sb = stat + b * 2 * NMEL;
        float4 v = out4[e4];
        v.x = (v.x - sb[m + 0]) * sb[NMEL + m + 0];
        v.y = (v.y - sb[m + 1]) * sb[NMEL + m + 1];
        v.z = (v.z - sb[m + 2]) * sb[NMEL + m + 2];
        v.w = (v.w - sb[m + 3]) * sb[NMEL + m + 3];
        out4[e4] = v;
    }
    const int nmask = B * (F / 2);
    float* mask = out + (size_t)B * F * NMEL;
    for (int e = blockIdx.x * blockDim.x + threadIdx.x; e < nmask; e += stride)
        mask[e] = 1.0f;
}

extern "C" void kernel_launch(void* const* d_in, const int* in_sizes, int n_in,
                              void* d_out, int out_size, void* d_ws, size_t ws_size,
                              hipStream_t stream) {
    const float* wav = (const float*)d_in[0];
    const float* fil = (const float*)d_in[1];
    const float* win = (const float*)d_in[2];
    float* out = (float*)d_out;
    float* ws = (float*)d_ws;

    setup_kernel<<<53, 256, 0, stream>>>(fil, ws);
    gemm_logmel_kernel<<<NBLK, 512, 0, stream>>>(wav, win, ws, out);  // 1504 blocks
    stats_final_kernel<<<B, 128, 0, stream>>>(ws);
    norm_mask_kernel<<<2048, 256, 0, stream>>>(out, ws);
}

// Round 15
// 134.688 us; speedup vs baseline: 1.2910x; 1.2910x over previous
//
#include <hip/hip_runtime.h>
#include <math.h>

#define FRAME_LEN 400
#define NBINS 257
#define NMEL 80
#define MEL_FLOOR 1.192092955078125e-07f

constexpr int B = 16;
constexpr int T = 480000;
constexpr int F = 1 + (T - FRAME_LEN) / 160; // 2998
constexpr int FRB = 8;                        // frames per block
constexpr int BPB = (F + FRB - 1) / FRB;      // 375 blocks per batch
constexpr int NBLK = B * BPB;                 // 6000

// ws float offsets
#define WS_TW256C 0      // 256
#define WS_TW256S 256
#define WS_TW64C  512    // 32
#define WS_TW64S  544
#define WS_UNP4C  576    // float4[64]
#define WS_UNP4S  832
#define WS_K0     1088   // int[80]
#define WS_LEN    1168   // int[80]
#define WS_WGT    1280   // float[32*80] -> ends 3840
#define WS_ACC    3840   // float[16][2][80] atomic accumulators -> ends 6400
#define WS_STAT   6400   // float[16][2][80] mean/invstd -> ends 8960
#define WS_PART   9216   // float[6000][2][80] = 960000 -> ends 969216
constexpr size_t WS_NEED_PART = (size_t)(WS_PART + NBLK * 160) * 4;

__device__ __forceinline__ int brev6(int x) { return (int)(__brev((unsigned)x) >> 26); }
__device__ __forceinline__ int specIdx(int k) { return k + ((k >> 5) << 2); }

// ---------------- Kernel 0: build tables + zero atomic accumulators ----------------
__global__ __launch_bounds__(256) void setup_kernel(
    const float* __restrict__ fil, float* __restrict__ ws)
{
    const int t = threadIdx.x;
    float s, c;
    sincosf(-6.283185307179586f * (float)t / 256.0f, &s, &c);
    ws[WS_TW256C + t] = c; ws[WS_TW256S + t] = s;
    if (t < 32) {
        sincosf(-6.283185307179586f * (float)t / 64.0f, &s, &c);
        ws[WS_TW64C + t] = c; ws[WS_TW64S + t] = s;
    }
    if (t < 64) {
        int m = brev6(t);
        for (int j = 0; j < 4; ++j) {
            sincosf(-6.283185307179586f * (float)(4 * m + j) / 512.0f, &s, &c);
            ws[WS_UNP4C + 4 * t + j] = c;
            ws[WS_UNP4S + 4 * t + j] = s;
        }
    }
    for (int i = t; i < 2560; i += 256) ws[WS_ACC + i] = 0.0f;  // zero accumulators
    // sparse mel compaction
    __shared__ int sh_k0[3][NMEL], sh_k1[3][NMEL];
    __shared__ int sh_K0[NMEL], sh_LEN[NMEL];
    if (t < 240) {
        int m = t % NMEL, r = t / NMEL;
        int kb = r * 86, ke = (kb + 86 < NBINS) ? (kb + 86) : NBINS;
        int k0 = -1, k1 = -1;
        for (int k = kb; k < ke; ++k) {
            if (fil[k * NMEL + m] > 0.0f) { if (k0 < 0) k0 = k; k1 = k; }
        }
        sh_k0[r][m] = k0; sh_k1[r][m] = k1;
    }
    __syncthreads();
    if (t < NMEL) {
        int k0 = -1, k1 = -1;
        for (int r = 0; r < 3; ++r) {
            int a = sh_k0[r][t], b1 = sh_k1[r][t];
            if (a >= 0) { if (k0 < 0) k0 = a; k1 = b1; }
        }
        int len = (k0 < 0) ? 0 : (k1 - k0 + 1);
        if (len > 32) len = 32;
        if (k0 < 0) k0 = 0;
        ((int*)ws)[WS_K0 + t] = k0;
        ((int*)ws)[WS_LEN + t] = len;
        sh_K0[t] = k0; sh_LEN[t] = len;
    }
    __syncthreads();
    for (int idx = t; idx < 32 * NMEL; idx += 256) {
        int j = idx / NMEL, m = idx - j * NMEL;
        ws[WS_WGT + idx] = (j < sh_LEN[m]) ? fil[(sh_K0[m] + j) * NMEL + m] : 0.0f;
    }
}

// ---------------- Kernel 1: wave-per-frame log-mel (8 frames/block) + fused stats ----------------
__global__ __launch_bounds__(512, 8) void frame_logmel_kernel(
    const float* __restrict__ wav,
    const float* __restrict__ win,
    float* __restrict__ ws,
    float* __restrict__ mel_out,
    int partMode)
{
    __shared__ float s_t256c[256], s_t256s[256];
    __shared__ float s_t64c[32], s_t64s[32];
    __shared__ float4 s_upc[64], s_ups[64];
    __shared__ float s_wgt[32 * NMEL];
    __shared__ int s_k0[NMEL], s_len[NMEL];
    __shared__ float2 s_win2[200];
    __shared__ float s_spec[FRB][296];
    __shared__ float s_ss[FRB][NMEL], s_ss2[FRB][NMEL];

    const int t = threadIdx.x;
    if (t < 256) {
        s_t256c[t] = ws[WS_TW256C + t];
        s_t256s[t] = ws[WS_TW256S + t];
    }
    if (t < 32) { s_t64c[t] = ws[WS_TW64C + t]; s_t64s[t] = ws[WS_TW64S + t]; }
    if (t < 64) {
        s_upc[t] = ((const float4*)(ws + WS_UNP4C))[t];
        s_ups[t] = ((const float4*)(ws + WS_UNP4S))[t];
    }
    for (int i = t; i < 32 * NMEL; i += 512) s_wgt[i] = ws[WS_WGT + i];
    if (t < NMEL) { s_k0[t] = ((const int*)ws)[WS_K0 + t]; s_len[t] = ((const int*)ws)[WS_LEN + t]; }
    if (t < 200) s_win2[t] = ((const float2*)win)[t];
    __syncthreads();  // tables ready

    const int l = t & 63, w = t >> 6;
    const int bid = blockIdx.x;
    const int b = bid / BPB, blk = bid - b * BPB;
    const int f = blk * FRB + w;
    const bool live = (f < F);
    const float2* src = (const float2*)(wav + (size_t)b * T + (size_t)(live ? f : 0) * 160);

    // load frame (complex-packed pairs), per-wave mean
    float xr[4], xi[4];
    float sum = 0.0f;
    #pragma unroll
    for (int j = 0; j < 4; ++j) {
        int p = 64 * j + l;
        float2 v = (live && p < 200) ? src[p] : make_float2(0.0f, 0.0f);
        xr[j] = v.x * 32768.0f;
        xi[j] = v.y * 32768.0f;
        sum += xr[j] + xi[j];
    }
    #pragma unroll
    for (int m = 32; m >= 1; m >>= 1) sum += __shfl_xor(sum, m);
    const float mean = sum * (1.0f / 400.0f);

    // preemphasis + window
    float zr[4], zi[4];
    float carry = 0.0f;
    #pragma unroll
    for (int j = 0; j < 4; ++j) {
        float y = xi[j], x0 = xr[j];
        float up = __shfl(y, (l + 63) & 63);
        float nc = __shfl(y, 63);
        if (l == 0) up = (j == 0) ? x0 : carry;
        carry = nc;
        int p = 64 * j + l;
        float2 w2 = (p < 200) ? s_win2[p] : make_float2(0.0f, 0.0f);
        zr[j] = (x0 - 0.97f * up - 0.03f * mean) * w2.x;
        zi[j] = (y - 0.97f * x0 - 0.03f * mean) * w2.y;
    }

    // in-lane radix-4 first stage + W_256^{j*l}
    float Ar = zr[0] + zr[2], Ai = zi[0] + zi[2];
    float Br = zr[0] - zr[2], Bi = zi[0] - zi[2];
    float Cr = zr[1] + zr[3], Ci = zi[1] + zi[3];
    float Dr = zr[1] - zr[3], Di = zi[1] - zi[3];
    float u0r = Ar + Cr, u0i = Ai + Ci;
    float u1r = Br + Di, u1i = Bi - Dr;
    float u2r = Ar - Cr, u2i = Ai - Ci;
    float u3r = Br - Di, u3i = Bi + Dr;
    {
        float wr, wi, tr;
        wr = s_t256c[l];     wi = s_t256s[l];
        tr = u1r * wr - u1i * wi; u1i = u1r * wi + u1i * wr; u1r = tr;
        wr = s_t256c[2 * l]; wi = s_t256s[2 * l];
        tr = u2r * wr - u2i * wi; u2i = u2r * wi + u2i * wr; u2r = tr;
        wr = s_t256c[3 * l]; wi = s_t256s[3 * l];
        tr = u3r * wr - u3i * wi; u3i = u3r * wi + u3i * wr; u3r = tr;
    }

    // 4x 64-pt FFT across lanes (radix-2 DIF via shfl_xor)
    #pragma unroll
    for (int h = 32; h >= 1; h >>= 1) {
        int idx = (l & (h - 1)) * (32 / h);
        bool hi = (l & h) != 0;
        float wr = hi ? s_t64c[idx] : 1.0f;
        float wi = hi ? s_t64s[idx] : 0.0f;
        float sg = hi ? -1.0f : 1.0f;
        #define BFLY(vr, vi)                                        \
        {                                                           \
            float pr = __shfl_xor(vr, h), pi = __shfl_xor(vi, h);   \
            float sr = fmaf(sg, vr, pr), si = fmaf(sg, vi, pi);     \
            vr = sr * wr - si * wi;                                 \
            vi = sr * wi + si * wr;                                 \
        }
        BFLY(u0r, u0i) BFLY(u1r, u1i) BFLY(u2r, u2i) BFLY(u3r, u3i)
        #undef BFLY
    }

    // real-FFT unpack in-register, power spectrum
    const int m = brev6(l);
    float b1r = __shfl_xor(u3r, 63), b1i = __shfl_xor(u3i, 63);
    float b2r = __shfl_xor(u2r, 63), b2i = __shfl_xor(u2i, 63);
    float b3r = __shfl_xor(u1r, 63), b3i = __shfl_xor(u1i, 63);
    int l0 = brev6((64 - m) & 63);
    float b0r = __shfl(u0r, l0), b0i = __shfl(u0i, l0);
    float4 wc = s_upc[l], wn = s_ups[l];
    float sp[4];
    #define UNP(J, ar, ai, br, bi, twr, twi)                        \
    {                                                               \
        float Er = 0.5f * (ar + br), Ei = 0.5f * (ai - bi);         \
        float Or = 0.5f * (ai + bi), Oi = 0.5f * (br - ar);         \
        float Xr = Er + twr * Or - twi * Oi;                        \
        float Xi = Ei + twr * Oi + twi * Or;                        \
        sp[J] = Xr * Xr + Xi * Xi;                                  \
    }
    UNP(0, u0r, u0i, b0r, b0i, wc.x, wn.x)
    UNP(1, u1r, u1i, b1r, b1i, wc.y, wn.y)
    UNP(2, u2r, u2i, b2r, b2i, wc.z, wn.z)
    UNP(3, u3r, u3i, b3r, b3i, wc.w, wn.w)
    #undef UNP
    ((float4*)s_spec[w])[m + (m >> 3)] = make_float4(sp[0], sp[1], sp[2], sp[3]);
    if (l == 0) {
        float d = u0r - u0i;  // X[256] = Re(Z0) - Im(Z0)
        s_spec[w][specIdx(256)] = d * d;
    }

    // sparse mel projection (wave-private spec; no barrier needed)
    const size_t outbase = (size_t)(b * F + f) * NMEL;
    float mv0, mv1 = 0.0f;
    {
        int mel = l;
        int k0 = s_k0[mel], len = s_len[mel];
        float acc = 0.0f;
        for (int i = 0; i < len; ++i)
            acc = fmaf(s_spec[w][specIdx(k0 + i)], s_wgt[i * NMEL + mel], acc);
        mv0 = __logf(fmaxf(acc, MEL_FLOOR));
        if (live) mel_out[outbase + mel] = mv0;
    }
    if (l < 16) {
        int mel = 64 + l;
        int k0 = s_k0[mel], len = s_len[mel];
        float acc = 0.0f;
        for (int i = 0; i < len; ++i)
            acc = fmaf(s_spec[w][specIdx(k0 + i)], s_wgt[i * NMEL + mel], acc);
        mv1 = __logf(fmaxf(acc, MEL_FLOOR));
        if (live) mel_out[outbase + mel] = mv1;
    }

    // fused stats partials: per-block sums over the 8 frames
    {
        float v0 = live ? mv0 : 0.0f;
        s_ss[w][l] = v0;
        s_ss2[w][l] = v0 * v0;
        if (l < 16) {
            float v1 = live ? mv1 : 0.0f;
            s_ss[w][64 + l] = v1;
            s_ss2[w][64 + l] = v1 * v1;
        }
    }
    __syncthreads();
    if (t < 160) {
        const int mel = (t < 80) ? t : (t - 80);
        float s = 0.0f;
        if (t < 80) {
            #pragma unroll
            for (int i = 0; i < FRB; ++i) s += s_ss[i][mel];
        } else {
            #pragma unroll
            for (int i = 0; i < FRB; ++i) s += s_ss2[i][mel];
        }
        if (partMode)
            ws[WS_PART + (size_t)bid * 160 + t] = s;
        else
            atomicAdd(&ws[WS_ACC + b * 160 + t], s);
    }
}

// ---------------- Kernel 2: finalize stats ----------------
__global__ __launch_bounds__(128) void stats_final_kernel(float* __restrict__ ws, int partMode)
{
    const int b = blockIdx.x;
    const int m = threadIdx.x;
    if (m >= NMEL) return;
    double s = 0.0, s2 = 0.0;
    if (partMode) {
        for (int c = 0; c < BPB; ++c) {
            const float* base = ws + WS_PART + (size_t)(b * BPB + c) * 160;
            s += (double)base[m];
            s2 += (double)base[80 + m];
        }
    } else {
        s = (double)ws[WS_ACC + b * 160 + m];
        s2 = (double)ws[WS_ACC + b * 160 + 80 + m];
    }
    double mean = s / (double)F;
    double var = (s2 - s * s / (double)F) / (double)(F - 1);
    ws[WS_STAT + b * 160 + m] = (float)mean;
    ws[WS_STAT + b * 160 + 80 + m] = (float)(1.0 / sqrt(var + 1e-7));
}

// ---------------- Kernel 3: normalize (float4) + mask ----------------
__global__ __launch_bounds__(256) void norm_mask_kernel(
    float* __restrict__ out, const float* __restrict__ ws)
{
    const float* stat = ws + WS_STAT;
    const int total4 = (B * F * NMEL) / 4;
    const int stride = gridDim.x * blockDim.x;
    float4* out4 = (float4*)out;
    for (int e4 = blockIdx.x * blockDim.x + threadIdx.x; e4 < total4; e4 += stride) {
        int e = e4 * 4;
        int b = e / (F * NMEL);
        int m = e % NMEL;
        const float* sb = stat + b * 160;
        float4 v = out4[e4];
        v.x = (v.x - sb[m + 0]) * sb[80 + m + 0];
        v.y = (v.y - sb[m + 1]) * sb[80 + m + 1];
        v.z = (v.z - sb[m + 2]) * sb[80 + m + 2];
        v.w = (v.w - sb[m + 3]) * sb[80 + m + 3];
        out4[e4] = v;
    }
    const int nmask = B * (F / 2);
    float* mask = out + (size_t)B * F * NMEL;
    for (int e = blockIdx.x * blockDim.x + threadIdx.x; e < nmask; e += stride)
        mask[e] = 1.0f;
}

extern "C" void kernel_launch(void* const* d_in, const int* in_sizes, int n_in,
                              void* d_out, int out_size, void* d_ws, size_t ws_size,
                              hipStream_t stream) {
    const float* wav = (const float*)d_in[0];
    const float* fil = (const float*)d_in[1];
    const float* win = (const float*)d_in[2];
    float* out = (float*)d_out;
    float* ws = (float*)d_ws;

    const int partMode = (ws_size >= WS_NEED_PART) ? 1 : 0;

    setup_kernel<<<1, 256, 0, stream>>>(fil, ws);
    frame_logmel_kernel<<<NBLK, 512, 0, stream>>>(wav, win, ws, out, partMode);
    stats_final_kernel<<<B, 128, 0, stream>>>(ws, partMode);
    norm_mask_kernel<<<2048, 256, 0, stream>>>(out, ws);
}

// Round 16
// 122.809 us; speedup vs baseline: 1.4159x; 1.0967x over previous
//
#include <hip/hip_runtime.h>
#include <math.h>

#define FRAME_LEN 400
#define NBINS 257
#define NMEL 80
#define MEL_FLOOR 1.192092955078125e-07f

constexpr int B = 16;
constexpr int T = 480000;
constexpr int F = 1 + (T - FRAME_LEN) / 160; // 2998
constexpr int FRB = 8;                        // frames per block
constexpr int BPB = (F + FRB - 1) / FRB;      // 375 blocks per batch
constexpr int NBLK = B * BPB;                 // 6000

// ws float offsets
#define WS_TW256C 0      // 256
#define WS_TW256S 256
#define WS_TW64C  512    // 32
#define WS_TW64S  544
#define WS_UNP4C  576    // float4[64]
#define WS_UNP4S  832
#define WS_K0     1088   // int[80]
#define WS_LEN    1168   // int[80]
#define WS_WGT    1280   // float[32*80] -> ends 3840
#define WS_ACC    3840   // float[16][2][80] atomic accumulators -> ends 6400
#define WS_STAT   6400   // float[16][2][80] mean/invstd -> ends 8960
#define WS_PART   9216   // float[6000][2][80] = 960000 -> ends 969216
constexpr size_t WS_NEED_PART = (size_t)(WS_PART + NBLK * 160) * 4;

__device__ __forceinline__ int brev6(int x) { return (int)(__brev((unsigned)x) >> 26); }
__device__ __forceinline__ int specIdx(int k) { return k + ((k >> 5) << 2); }

// ---------------- Kernel 0: build tables + zero atomic accumulators ----------------
__global__ __launch_bounds__(256) void setup_kernel(
    const float* __restrict__ fil, float* __restrict__ ws)
{
    const int t = threadIdx.x;
    float s, c;
    sincosf(-6.283185307179586f * (float)t / 256.0f, &s, &c);
    ws[WS_TW256C + t] = c; ws[WS_TW256S + t] = s;
    if (t < 32) {
        sincosf(-6.283185307179586f * (float)t / 64.0f, &s, &c);
        ws[WS_TW64C + t] = c; ws[WS_TW64S + t] = s;
    }
    if (t < 64) {
        int m = brev6(t);
        for (int j = 0; j < 4; ++j) {
            sincosf(-6.283185307179586f * (float)(4 * m + j) / 512.0f, &s, &c);
            ws[WS_UNP4C + 4 * t + j] = c;
            ws[WS_UNP4S + 4 * t + j] = s;
        }
    }
    for (int i = t; i < 2560; i += 256) ws[WS_ACC + i] = 0.0f;  // zero accumulators
    // sparse mel compaction
    __shared__ int sh_k0[3][NMEL], sh_k1[3][NMEL];
    __shared__ int sh_K0[NMEL], sh_LEN[NMEL];
    if (t < 240) {
        int m = t % NMEL, r = t / NMEL;
        int kb = r * 86, ke = (kb + 86 < NBINS) ? (kb + 86) : NBINS;
        int k0 = -1, k1 = -1;
        for (int k = kb; k < ke; ++k) {
            if (fil[k * NMEL + m] > 0.0f) { if (k0 < 0) k0 = k; k1 = k; }
        }
        sh_k0[r][m] = k0; sh_k1[r][m] = k1;
    }
    __syncthreads();
    if (t < NMEL) {
        int k0 = -1, k1 = -1;
        for (int r = 0; r < 3; ++r) {
            int a = sh_k0[r][t], b1 = sh_k1[r][t];
            if (a >= 0) { if (k0 < 0) k0 = a; k1 = b1; }
        }
        int len = (k0 < 0) ? 0 : (k1 - k0 + 1);
        if (len > 32) len = 32;
        if (k0 < 0) k0 = 0;
        ((int*)ws)[WS_K0 + t] = k0;
        ((int*)ws)[WS_LEN + t] = len;
        sh_K0[t] = k0; sh_LEN[t] = len;
    }
    __syncthreads();
    for (int idx = t; idx < 32 * NMEL; idx += 256) {
        int j = idx / NMEL, m = idx - j * NMEL;
        ws[WS_WGT + idx] = (j < sh_LEN[m]) ? fil[(sh_K0[m] + j) * NMEL + m] : 0.0f;
    }
}

// ---------------- Kernel 1: wave-per-frame log-mel (8 frames/block) + fused stats ----------------
__global__ __launch_bounds__(512, 8) void frame_logmel_kernel(
    const float* __restrict__ wav,
    const float* __restrict__ win,
    float* __restrict__ ws,
    float* __restrict__ mel_out,
    int partMode)
{
    __shared__ float s_t256c[256], s_t256s[256];
    __shared__ float s_t64c[32], s_t64s[32];
    __shared__ float4 s_upc[64], s_ups[64];
    __shared__ float s_wgt[32 * NMEL];
    __shared__ int s_k0[NMEL], s_len[NMEL];
    __shared__ float2 s_win2[200];
    __shared__ float s_spec[FRB][296];
    __shared__ float s_ss[FRB][NMEL], s_ss2[FRB][NMEL];

    const int t = threadIdx.x;
    if (t < 256) {
        s_t256c[t] = ws[WS_TW256C + t];
        s_t256s[t] = ws[WS_TW256S + t];
    }
    if (t < 32) { s_t64c[t] = ws[WS_TW64C + t]; s_t64s[t] = ws[WS_TW64S + t]; }
    if (t < 64) {
        s_upc[t] = ((const float4*)(ws + WS_UNP4C))[t];
        s_ups[t] = ((const float4*)(ws + WS_UNP4S))[t];
    }
    for (int i = t; i < 32 * NMEL; i += 512) s_wgt[i] = ws[WS_WGT + i];
    if (t < NMEL) { s_k0[t] = ((const int*)ws)[WS_K0 + t]; s_len[t] = ((const int*)ws)[WS_LEN + t]; }
    if (t < 200) s_win2[t] = ((const float2*)win)[t];
    __syncthreads();  // tables ready

    const int l = t & 63, w = t >> 6;
    const int bid = blockIdx.x;
    const int b = bid / BPB, blk = bid - b * BPB;
    const int f = blk * FRB + w;
    const bool live = (f < F);
    const float2* src = (const float2*)(wav + (size_t)b * T + (size_t)(live ? f : 0) * 160);

    // load frame (complex-packed pairs), per-wave mean
    float xr[4], xi[4];
    float sum = 0.0f;
    #pragma unroll
    for (int j = 0; j < 4; ++j) {
        int p = 64 * j + l;
        float2 v = (live && p < 200) ? src[p] : make_float2(0.0f, 0.0f);
        xr[j] = v.x * 32768.0f;
        xi[j] = v.y * 32768.0f;
        sum += xr[j] + xi[j];
    }
    #pragma unroll
    for (int m = 32; m >= 1; m >>= 1) sum += __shfl_xor(sum, m);
    const float mean = sum * (1.0f / 400.0f);

    // preemphasis + window
    float zr[4], zi[4];
    float carry = 0.0f;
    #pragma unroll
    for (int j = 0; j < 4; ++j) {
        float y = xi[j], x0 = xr[j];
        float up = __shfl(y, (l + 63) & 63);
        float nc = __shfl(y, 63);
        if (l == 0) up = (j == 0) ? x0 : carry;
        carry = nc;
        int p = 64 * j + l;
        float2 w2 = (p < 200) ? s_win2[p] : make_float2(0.0f, 0.0f);
        zr[j] = (x0 - 0.97f * up - 0.03f * mean) * w2.x;
        zi[j] = (y - 0.97f * x0 - 0.03f * mean) * w2.y;
    }

    // in-lane radix-4 first stage + W_256^{j*l}
    float Ar = zr[0] + zr[2], Ai = zi[0] + zi[2];
    float Br = zr[0] - zr[2], Bi = zi[0] - zi[2];
    float Cr = zr[1] + zr[3], Ci = zi[1] + zi[3];
    float Dr = zr[1] - zr[3], Di = zi[1] - zi[3];
    float u0r = Ar + Cr, u0i = Ai + Ci;
    float u1r = Br + Di, u1i = Bi - Dr;
    float u2r = Ar - Cr, u2i = Ai - Ci;
    float u3r = Br - Di, u3i = Bi + Dr;
    {
        float wr, wi, tr;
        wr = s_t256c[l];     wi = s_t256s[l];
        tr = u1r * wr - u1i * wi; u1i = u1r * wi + u1i * wr; u1r = tr;
        wr = s_t256c[2 * l]; wi = s_t256s[2 * l];
        tr = u2r * wr - u2i * wi; u2i = u2r * wi + u2i * wr; u2r = tr;
        wr = s_t256c[3 * l]; wi = s_t256s[3 * l];
        tr = u3r * wr - u3i * wi; u3i = u3r * wi + u3i * wr; u3r = tr;
    }

    // 4x 64-pt FFT across lanes (radix-2 DIF via shfl_xor)
    #pragma unroll
    for (int h = 32; h >= 1; h >>= 1) {
        int idx = (l & (h - 1)) * (32 / h);
        bool hi = (l & h) != 0;
        float wr = hi ? s_t64c[idx] : 1.0f;
        float wi = hi ? s_t64s[idx] : 0.0f;
        float sg = hi ? -1.0f : 1.0f;
        #define BFLY(vr, vi)                                        \
        {                                                           \
            float pr = __shfl_xor(vr, h), pi = __shfl_xor(vi, h);   \
            float sr = fmaf(sg, vr, pr), si = fmaf(sg, vi, pi);     \
            vr = sr * wr - si * wi;                                 \
            vi = sr * wi + si * wr;                                 \
        }
        BFLY(u0r, u0i) BFLY(u1r, u1i) BFLY(u2r, u2i) BFLY(u3r, u3i)
        #undef BFLY
    }

    // real-FFT unpack in-register, power spectrum
    const int m = brev6(l);
    float b1r = __shfl_xor(u3r, 63), b1i = __shfl_xor(u3i, 63);
    float b2r = __shfl_xor(u2r, 63), b2i = __shfl_xor(u2i, 63);
    float b3r = __shfl_xor(u1r, 63), b3i = __shfl_xor(u1i, 63);
    int l0 = brev6((64 - m) & 63);
    float b0r = __shfl(u0r, l0), b0i = __shfl(u0i, l0);
    float4 wc = s_upc[l], wn = s_ups[l];
    float sp[4];
    #define UNP(J, ar, ai, br, bi, twr, twi)                        \
    {                                                               \
        float Er = 0.5f * (ar + br), Ei = 0.5f * (ai - bi);         \
        float Or = 0.5f * (ai + bi), Oi = 0.5f * (br - ar);         \
        float Xr = Er + twr * Or - twi * Oi;                        \
        float Xi = Ei + twr * Oi + twi * Or;                        \
        sp[J] = Xr * Xr + Xi * Xi;                                  \
    }
    UNP(0, u0r, u0i, b0r, b0i, wc.x, wn.x)
    UNP(1, u1r, u1i, b1r, b1i, wc.y, wn.y)
    UNP(2, u2r, u2i, b2r, b2i, wc.z, wn.z)
    UNP(3, u3r, u3i, b3r, b3i, wc.w, wn.w)
    #undef UNP
    ((float4*)s_spec[w])[m + (m >> 3)] = make_float4(sp[0], sp[1], sp[2], sp[3]);
    if (l == 0) {
        float d = u0r - u0i;  // X[256] = Re(Z0) - Im(Z0)
        s_spec[w][specIdx(256)] = d * d;
    }

    // sparse mel projection (wave-private spec; no barrier needed)
    const size_t outbase = (size_t)(b * F + f) * NMEL;
    float mv0, mv1 = 0.0f;
    {
        int mel = l;
        int k0 = s_k0[mel], len = s_len[mel];
        float acc = 0.0f;
        for (int i = 0; i < len; ++i)
            acc = fmaf(s_spec[w][specIdx(k0 + i)], s_wgt[i * NMEL + mel], acc);
        mv0 = __logf(fmaxf(acc, MEL_FLOOR));
        if (live) mel_out[outbase + mel] = mv0;
    }
    if (l < 16) {
        int mel = 64 + l;
        int k0 = s_k0[mel], len = s_len[mel];
        float acc = 0.0f;
        for (int i = 0; i < len; ++i)
            acc = fmaf(s_spec[w][specIdx(k0 + i)], s_wgt[i * NMEL + mel], acc);
        mv1 = __logf(fmaxf(acc, MEL_FLOOR));
        if (live) mel_out[outbase + mel] = mv1;
    }

    // fused stats partials: per-block sums over the 8 frames
    {
        float v0 = live ? mv0 : 0.0f;
        s_ss[w][l] = v0;
        s_ss2[w][l] = v0 * v0;
        if (l < 16) {
            float v1 = live ? mv1 : 0.0f;
            s_ss[w][64 + l] = v1;
            s_ss2[w][64 + l] = v1 * v1;
        }
    }
    __syncthreads();
    if (t < 160) {
        const int mel = (t < 80) ? t : (t - 80);
        float s = 0.0f;
        if (t < 80) {
            #pragma unroll
            for (int i = 0; i < FRB; ++i) s += s_ss[i][mel];
        } else {
            #pragma unroll
            for (int i = 0; i < FRB; ++i) s += s_ss2[i][mel];
        }
        if (partMode)
            ws[WS_PART + (size_t)bid * 160 + t] = s;
        else
            atomicAdd(&ws[WS_ACC + b * 160 + t], s);
    }
}

// ---------------- Kernel 2: finalize stats (parallel over 8 rows) ----------------
__global__ __launch_bounds__(640) void stats_final_kernel(float* __restrict__ ws, int partMode)
{
    const int b = blockIdx.x;
    const int m = threadIdx.x;   // 0..79
    const int r = threadIdx.y;   // 0..7
    __shared__ float shs[8][NMEL], shs2[8][NMEL];
    float s = 0.0f, s2 = 0.0f;
    if (partMode) {
        for (int c = r; c < BPB; c += 8) {
            const float* base = ws + WS_PART + (size_t)(b * BPB + c) * 160;
            s += base[m];
            s2 += base[80 + m];
        }
    }
    shs[r][m] = s; shs2[r][m] = s2;
    __syncthreads();
    if (r == 0) {
        double ds = 0.0, ds2 = 0.0;
        if (partMode) {
            #pragma unroll
            for (int i = 0; i < 8; ++i) { ds += (double)shs[i][m]; ds2 += (double)shs2[i][m]; }
        } else {
            ds = (double)ws[WS_ACC + b * 160 + m];
            ds2 = (double)ws[WS_ACC + b * 160 + 80 + m];
        }
        double mean = ds / (double)F;
        double var = (ds2 - ds * ds / (double)F) / (double)(F - 1);
        ws[WS_STAT + b * 160 + m] = (float)mean;
        ws[WS_STAT + b * 160 + 80 + m] = (float)(1.0 / sqrt(var + 1e-7));
    }
}

// ---------------- Kernel 3: normalize (float4) + mask ----------------
__global__ __launch_bounds__(256) void norm_mask_kernel(
    float* __restrict__ out, const float* __restrict__ ws)
{
    const float* stat = ws + WS_STAT;
    const int total4 = (B * F * NMEL) / 4;
    const int stride = gridDim.x * blockDim.x;
    float4* out4 = (float4*)out;
    for (int e4 = blockIdx.x * blockDim.x + threadIdx.x; e4 < total4; e4 += stride) {
        int e = e4 * 4;
        int b = e / (F * NMEL);
        int m = e % NMEL;
        const float* sb = stat + b * 160;
        float4 v = out4[e4];
        v.x = (v.x - sb[m + 0]) * sb[80 + m + 0];
        v.y = (v.y - sb[m + 1]) * sb[80 + m + 1];
        v.z = (v.z - sb[m + 2]) * sb[80 + m + 2];
        v.w = (v.w - sb[m + 3]) * sb[80 + m + 3];
        out4[e4] = v;
    }
    const int nmask = B * (F / 2);
    float* mask = out + (size_t)B * F * NMEL;
    for (int e = blockIdx.x * blockDim.x + threadIdx.x; e < nmask; e += stride)
        mask[e] = 1.0f;
}

extern "C" void kernel_launch(void* const* d_in, const int* in_sizes, int n_in,
                              void* d_out, int out_size, void* d_ws, size_t ws_size,
                              hipStream_t stream) {
    const float* wav = (const float*)d_in[0];
    const float* fil = (const float*)d_in[1];
    const float* win = (const float*)d_in[2];
    float* out = (float*)d_out;
    float* ws = (float*)d_ws;

    const int partMode = (ws_size >= WS_NEED_PART) ? 1 : 0;

    setup_kernel<<<1, 256, 0, stream>>>(fil, ws);
    frame_logmel_kernel<<<NBLK, 512, 0, stream>>>(wav, win, ws, out, partMode);
    stats_final_kernel<<<B, dim3(NMEL, 8), 0, stream>>>(ws, partMode);
    norm_mask_kernel<<<2048, 256, 0, stream>>>(out, ws);
}

// Round 18
// 113.303 us; speedup vs baseline: 1.5347x; 1.0839x over previous
//
#include <hip/hip_runtime.h>
#include <math.h>

#define FRAME_LEN 400
#define NBINS 257
#define NMEL 80
#define MEL_FLOOR 1.192092955078125e-07f

constexpr int B = 16;
constexpr int T = 480000;
constexpr int F = 1 + (T - FRAME_LEN) / 160; // 2998
constexpr int FRB = 16;                       // frames per block
constexpr int BPB = (F + FRB - 1) / FRB;      // 188 blocks per batch
constexpr int NBLK = B * BPB;                 // 3008

// ws float offsets
#define WS_TW256C 0      // 256
#define WS_TW256S 256
#define WS_TW64C  512    // 32
#define WS_TW64S  544
#define WS_UNP4C  576    // float4[64]
#define WS_UNP4S  832
#define WS_K0     1088   // int[80]
#define WS_LEN    1168   // int[80]
#define WS_WGT    1280   // float[32*80] -> ends 3840
#define WS_ACC    3840   // float[16][2][80] atomic accumulators -> ends 6400
#define WS_STAT   6400   // float[16][2][80] mean/invstd -> ends 8960
#define WS_PART   9216   // float[3008][2][80] = 481280 -> ends 490496
constexpr size_t WS_NEED_PART = (size_t)(WS_PART + NBLK * 160) * 4;

__device__ __forceinline__ int brev6(int x) { return (int)(__brev((unsigned)x) >> 26); }
__device__ __forceinline__ int specIdx(int k) { return k + ((k >> 5) << 2); }

// ---------------- Kernel 0: build tables + zero atomic accumulators ----------------
__global__ __launch_bounds__(256) void setup_kernel(
    const float* __restrict__ fil, float* __restrict__ ws)
{
    const int t = threadIdx.x;
    float s, c;
    sincosf(-6.283185307179586f * (float)t / 256.0f, &s, &c);
    ws[WS_TW256C + t] = c; ws[WS_TW256S + t] = s;
    if (t < 32) {
        sincosf(-6.283185307179586f * (float)t / 64.0f, &s, &c);
        ws[WS_TW64C + t] = c; ws[WS_TW64S + t] = s;
    }
    if (t < 64) {
        int m = brev6(t);
        for (int j = 0; j < 4; ++j) {
            sincosf(-6.283185307179586f * (float)(4 * m + j) / 512.0f, &s, &c);
            ws[WS_UNP4C + 4 * t + j] = c;
            ws[WS_UNP4S + 4 * t + j] = s;
        }
    }
    for (int i = t; i < 2560; i += 256) ws[WS_ACC + i] = 0.0f;  // zero accumulators
    // sparse mel compaction
    __shared__ int sh_k0[3][NMEL], sh_k1[3][NMEL];
    __shared__ int sh_K0[NMEL], sh_LEN[NMEL];
    if (t < 240) {
        int m = t % NMEL, r = t / NMEL;
        int kb = r * 86, ke = (kb + 86 < NBINS) ? (kb + 86) : NBINS;
        int k0 = -1, k1 = -1;
        for (int k = kb; k < ke; ++k) {
            if (fil[k * NMEL + m] > 0.0f) { if (k0 < 0) k0 = k; k1 = k; }
        }
        sh_k0[r][m] = k0; sh_k1[r][m] = k1;
    }
    __syncthreads();
    if (t < NMEL) {
        int k0 = -1, k1 = -1;
        for (int r = 0; r < 3; ++r) {
            int a = sh_k0[r][t], b1 = sh_k1[r][t];
            if (a >= 0) { if (k0 < 0) k0 = a; k1 = b1; }
        }
        int len = (k0 < 0) ? 0 : (k1 - k0 + 1);
        if (len > 32) len = 32;
        if (k0 < 0) k0 = 0;
        ((int*)ws)[WS_K0 + t] = k0;
        ((int*)ws)[WS_LEN + t] = len;
        sh_K0[t] = k0; sh_LEN[t] = len;
    }
    __syncthreads();
    for (int idx = t; idx < 32 * NMEL; idx += 256) {
        int j = idx / NMEL, m = idx - j * NMEL;
        ws[WS_WGT + idx] = (j < sh_LEN[m]) ? fil[(sh_K0[m] + j) * NMEL + m] : 0.0f;
    }
}

// ---------------- Kernel 1: wave-per-frame log-mel (16 frames/block) + fused stats ----------------
__global__ __launch_bounds__(1024, 8) void frame_logmel_kernel(
    const float* __restrict__ wav,
    const float* __restrict__ win,
    float* __restrict__ ws,
    float* __restrict__ mel_out,
    int partMode)
{
    __shared__ float s_t256c[256], s_t256s[256];
    __shared__ float s_t64c[32], s_t64s[32];
    __shared__ float4 s_upc[64], s_ups[64];
    __shared__ float s_wgt[32 * NMEL];
    __shared__ int s_k0[NMEL], s_len[NMEL];
    __shared__ float2 s_win2[200];
    __shared__ float s_spec[FRB][296];
    __shared__ float s_ss[FRB][NMEL], s_ss2[FRB][NMEL];

    const int t = threadIdx.x;
    if (t < 256) {
        s_t256c[t] = ws[WS_TW256C + t];
        s_t256s[t] = ws[WS_TW256S + t];
    }
    if (t < 32) { s_t64c[t] = ws[WS_TW64C + t]; s_t64s[t] = ws[WS_TW64S + t]; }
    if (t < 64) {
        s_upc[t] = ((const float4*)(ws + WS_UNP4C))[t];
        s_ups[t] = ((const float4*)(ws + WS_UNP4S))[t];
    }
    for (int i = t; i < 32 * NMEL; i += 1024) s_wgt[i] = ws[WS_WGT + i];
    if (t < NMEL) { s_k0[t] = ((const int*)ws)[WS_K0 + t]; s_len[t] = ((const int*)ws)[WS_LEN + t]; }
    if (t < 200) s_win2[t] = ((const float2*)win)[t];
    __syncthreads();  // tables ready

    const int l = t & 63, w = t >> 6;
    const int bid = blockIdx.x;
    const int b = bid / BPB, blk = bid - b * BPB;
    const int f = blk * FRB + w;
    const bool live = (f < F);
    const float2* src = (const float2*)(wav + (size_t)b * T + (size_t)(live ? f : 0) * 160);

    // load frame (complex-packed pairs), per-wave mean
    float xr[4], xi[4];
    float sum = 0.0f;
    #pragma unroll
    for (int j = 0; j < 4; ++j) {
        int p = 64 * j + l;
        float2 v = (live && p < 200) ? src[p] : make_float2(0.0f, 0.0f);
        xr[j] = v.x * 32768.0f;
        xi[j] = v.y * 32768.0f;
        sum += xr[j] + xi[j];
    }
    #pragma unroll
    for (int m = 32; m >= 1; m >>= 1) sum += __shfl_xor(sum, m);
    const float mean = sum * (1.0f / 400.0f);

    // preemphasis + window
    float zr[4], zi[4];
    float carry = 0.0f;
    #pragma unroll
    for (int j = 0; j < 4; ++j) {
        float y = xi[j], x0 = xr[j];
        float up = __shfl(y, (l + 63) & 63);
        float nc = __shfl(y, 63);
        if (l == 0) up = (j == 0) ? x0 : carry;
        carry = nc;
        int p = 64 * j + l;
        float2 w2 = (p < 200) ? s_win2[p] : make_float2(0.0f, 0.0f);
        zr[j] = (x0 - 0.97f * up - 0.03f * mean) * w2.x;
        zi[j] = (y - 0.97f * x0 - 0.03f * mean) * w2.y;
    }

    // in-lane radix-4 first stage + W_256^{j*l}
    float Ar = zr[0] + zr[2], Ai = zi[0] + zi[2];
    float Br = zr[0] - zr[2], Bi = zi[0] - zi[2];
    float Cr = zr[1] + zr[3], Ci = zi[1] + zi[3];
    float Dr = zr[1] - zr[3], Di = zi[1] - zi[3];
    float u0r = Ar + Cr, u0i = Ai + Ci;
    float u1r = Br + Di, u1i = Bi - Dr;
    float u2r = Ar - Cr, u2i = Ai - Ci;
    float u3r = Br - Di, u3i = Bi + Dr;
    {
        float wr, wi, tr;
        wr = s_t256c[l];     wi = s_t256s[l];
        tr = u1r * wr - u1i * wi; u1i = u1r * wi + u1i * wr; u1r = tr;
        wr = s_t256c[2 * l]; wi = s_t256s[2 * l];
        tr = u2r * wr - u2i * wi; u2i = u2r * wi + u2i * wr; u2r = tr;
        wr = s_t256c[3 * l]; wi = s_t256s[3 * l];
        tr = u3r * wr - u3i * wi; u3i = u3r * wi + u3i * wr; u3r = tr;
    }

    // 4x 64-pt FFT across lanes (radix-2 DIF via shfl_xor)
    #pragma unroll
    for (int h = 32; h >= 1; h >>= 1) {
        int idx = (l & (h - 1)) * (32 / h);
        bool hi = (l & h) != 0;
        float wr = hi ? s_t64c[idx] : 1.0f;
        float wi = hi ? s_t64s[idx] : 0.0f;
        float sg = hi ? -1.0f : 1.0f;
        #define BFLY(vr, vi)                                        \
        {                                                           \
            float pr = __shfl_xor(vr, h), pi = __shfl_xor(vi, h);   \
            float sr = fmaf(sg, vr, pr), si = fmaf(sg, vi, pi);     \
            vr = sr * wr - si * wi;                                 \
            vi = sr * wi + si * wr;                                 \
        }
        BFLY(u0r, u0i) BFLY(u1r, u1i) BFLY(u2r, u2i) BFLY(u3r, u3i)
        #undef BFLY
    }

    // real-FFT unpack in-register, power spectrum
    const int m = brev6(l);
    float b1r = __shfl_xor(u3r, 63), b1i = __shfl_xor(u3i, 63);
    float b2r = __shfl_xor(u2r, 63), b2i = __shfl_xor(u2i, 63);
    float b3r = __shfl_xor(u1r, 63), b3i = __shfl_xor(u1i, 63);
    int l0 = brev6((64 - m) & 63);
    float b0r = __shfl(u0r, l0), b0i = __shfl(u0i, l0);
    float4 wc = s_upc[l], wn = s_ups[l];
    float sp[4];
    #define UNP(J, ar, ai, br, bi, twr, twi)                        \
    {                                                               \
        float Er = 0.5f * (ar + br), Ei = 0.5f * (ai - bi);         \
        float Or = 0.5f * (ai + bi), Oi = 0.5f * (br - ar);         \
        float Xr = Er + twr * Or - twi * Oi;                        \
        float Xi = Ei + twr * Oi + twi * Or;                        \
        sp[J] = Xr * Xr + Xi * Xi;                                  \
    }
    UNP(0, u0r, u0i, b0r, b0i, wc.x, wn.x)
    UNP(1, u1r, u1i, b1r, b1i, wc.y, wn.y)
    UNP(2, u2r, u2i, b2r, b2i, wc.z, wn.z)
    UNP(3, u3r, u3i, b3r, b3i, wc.w, wn.w)
    #undef UNP
    ((float4*)s_spec[w])[m + (m >> 3)] = make_float4(sp[0], sp[1], sp[2], sp[3]);
    if (l == 0) {
        float d = u0r - u0i;  // X[256] = Re(Z0) - Im(Z0)
        s_spec[w][specIdx(256)] = d * d;
    }

    // sparse mel projection (wave-private spec; no barrier needed)
    const size_t outbase = (size_t)(b * F + f) * NMEL;
    // narrow mels 0..63: one lane per mel
    float mv0;
    {
        int mel = l;
        int k0 = s_k0[mel], len = s_len[mel];
        float acc = 0.0f;
        for (int i = 0; i < len; ++i)
            acc = fmaf(s_spec[w][specIdx(k0 + i)], s_wgt[i * NMEL + mel], acc);
        mv0 = __logf(fmaxf(acc, MEL_FLOOR));
        if (live) mel_out[outbase + mel] = mv0;
    }
    // wide mels 64..79: 4 lanes per mel (lane q sums i ≡ q mod 4), shfl-combine
    float mv1 = 0.0f;
    const int q = l & 3;
    {
        int mel = 64 + (l >> 2);
        int k0 = s_k0[mel], len = s_len[mel];
        float acc = 0.0f;
        for (int i = q; i < len; i += 4)
            acc = fmaf(s_spec[w][specIdx(k0 + i)], s_wgt[i * NMEL + mel], acc);
        acc += __shfl_xor(acc, 1);
        acc += __shfl_xor(acc, 2);
        if (q == 0) {
            mv1 = __logf(fmaxf(acc, MEL_FLOOR));
            if (live) mel_out[outbase + mel] = mv1;
        }
    }

    // fused stats partials: per-block sums over the FRB frames
    {
        float v0 = live ? mv0 : 0.0f;
        s_ss[w][l] = v0;
        s_ss2[w][l] = v0 * v0;
        if (q == 0) {
            float v1 = live ? mv1 : 0.0f;
            s_ss[w][64 + (l >> 2)] = v1;
            s_ss2[w][64 + (l >> 2)] = v1 * v1;
        }
    }
    __syncthreads();
    if (t < 160) {
        const int mel = (t < 80) ? t : (t - 80);
        float s = 0.0f;
        if (t < 80) {
            #pragma unroll
            for (int i = 0; i < FRB; ++i) s += s_ss[i][mel];
        } else {
            #pragma unroll
            for (int i = 0; i < FRB; ++i) s += s_ss2[i][mel];
        }
        if (partMode)
            ws[WS_PART + (size_t)bid * 160 + t] = s;
        else
            atomicAdd(&ws[WS_ACC + b * 160 + t], s);
    }
}

// ---------------- Kernel 2: finalize stats (parallel over 8 rows) ----------------
__global__ __launch_bounds__(640) void stats_final_kernel(float* __restrict__ ws, int partMode)
{
    const int b = blockIdx.x;
    const int m = threadIdx.x;   // 0..79
    const int r = threadIdx.y;   // 0..7
    __shared__ float shs[8][NMEL], shs2[8][NMEL];
    float s = 0.0f, s2 = 0.0f;
    if (partMode) {
        for (int c = r; c < BPB; c += 8) {
            const float* base = ws + WS_PART + (size_t)(b * BPB + c) * 160;
            s += base[m];
            s2 += base[80 + m];
        }
    }
    shs[r][m] = s; shs2[r][m] = s2;
    __syncthreads();
    if (r == 0) {
        double ds = 0.0, ds2 = 0.0;
        if (partMode) {
            #pragma unroll
            for (int i = 0; i < 8; ++i) { ds += (double)shs[i][m]; ds2 += (double)shs2[i][m]; }
        } else {
            ds = (double)ws[WS_ACC + b * 160 + m];
            ds2 = (double)ws[WS_ACC + b * 160 + 80 + m];
        }
        double mean = ds / (double)F;
        double var = (ds2 - ds * ds / (double)F) / (double)(F - 1);
        ws[WS_STAT + b * 160 + m] = (float)mean;
        ws[WS_STAT + b * 160 + 80 + m] = (float)(1.0 / sqrt(var + 1e-7));
    }
}

// ---------------- Kernel 3: normalize (float4) + mask ----------------
__global__ __launch_bounds__(256) void norm_mask_kernel(
    float* __restrict__ out, const float* __restrict__ ws)
{
    const float* stat = ws + WS_STAT;
    const int total4 = (B * F * NMEL) / 4;
    const int stride = gridDim.x * blockDim.x;
    float4* out4 = (float4*)out;
    for (int e4 = blockIdx.x * blockDim.x + threadIdx.x; e4 < total4; e4 += stride) {
        int e = e4 * 4;
        int b = e / (F * NMEL);
        int m = e % NMEL;
        const float* sb = stat + b * 160;
        float4 v = out4[e4];
        v.x = (v.x - sb[m + 0]) * sb[80 + m + 0];
        v.y = (v.y - sb[m + 1]) * sb[80 + m + 1];
        v.z = (v.z - sb[m + 2]) * sb[80 + m + 2];
        v.w = (v.w - sb[m + 3]) * sb[80 + m + 3];
        out4[e4] = v;
    }
    const int nmask = B * (F / 2);
    float* mask = out + (size_t)B * F * NMEL;
    for (int e = blockIdx.x * blockDim.x + threadIdx.x; e < nmask; e += stride)
        mask[e] = 1.0f;
}

extern "C" void kernel_launch(void* const* d_in, const int* in_sizes, int n_in,
                              void* d_out, int out_size, void* d_ws, size_t ws_size,
                              hipStream_t stream) {
    const float* wav = (const float*)d_in[0];
    const float* fil = (const float*)d_in[1];
    const float* win = (const float*)d_in[2];
    float* out = (float*)d_out;
    float* ws = (float*)d_ws;

    const int partMode = (ws_size >= WS_NEED_PART) ? 1 : 0;

    setup_kernel<<<1, 256, 0, stream>>>(fil, ws);
    frame_logmel_kernel<<<NBLK, 1024, 0, stream>>>(wav, win, ws, out, partMode);
    stats_final_kernel<<<B, dim3(NMEL, 8), 0, stream>>>(ws, partMode);
    norm_mask_kernel<<<2048, 256, 0, stream>>>(out, ws);
}

// Round 19
// 110.706 us; speedup vs baseline: 1.5707x; 1.0235x over previous
//
#include <hip/hip_runtime.h>
#include <math.h>

#define FRAME_LEN 400
#define NBINS 257
#define NMEL 80
#define MEL_FLOOR 1.192092955078125e-07f

constexpr int B = 16;
constexpr int T = 480000;
constexpr int F = 1 + (T - FRAME_LEN) / 160; // 2998
constexpr int FRB = 16;                       // frames per block (8 waves x 2 frames)
constexpr int BPB = (F + FRB - 1) / FRB;      // 188 blocks per batch
constexpr int NBLK = B * BPB;                 // 3008

// ws float offsets
#define WS_TW256C 0      // 256
#define WS_TW256S 256
#define WS_TW64C  512    // 32
#define WS_TW64S  544
#define WS_UNP4C  576    // float4[64]
#define WS_UNP4S  832
#define WS_K0     1088   // int[80]
#define WS_LEN    1168   // int[80]
#define WS_WGT    1280   // float[32*80] -> ends 3840
#define WS_ACC    3840   // float[16][2][80] atomic accumulators -> ends 6400
#define WS_STAT   6400   // float[16][2][80] mean/invstd -> ends 8960
#define WS_PART   9216   // float[3008][2][80] = 481280 -> ends 490496
constexpr size_t WS_NEED_PART = (size_t)(WS_PART + NBLK * 160) * 4;

__device__ __forceinline__ int brev6(int x) { return (int)(__brev((unsigned)x) >> 26); }
__device__ __forceinline__ int specIdx(int k) { return k + ((k >> 5) << 2); }

// ---------------- Kernel 0: build tables + zero atomic accumulators ----------------
__global__ __launch_bounds__(256) void setup_kernel(
    const float* __restrict__ fil, float* __restrict__ ws)
{
    const int t = threadIdx.x;
    float s, c;
    sincosf(-6.283185307179586f * (float)t / 256.0f, &s, &c);
    ws[WS_TW256C + t] = c; ws[WS_TW256S + t] = s;
    if (t < 32) {
        sincosf(-6.283185307179586f * (float)t / 64.0f, &s, &c);
        ws[WS_TW64C + t] = c; ws[WS_TW64S + t] = s;
    }
    if (t < 64) {
        int m = brev6(t);
        for (int j = 0; j < 4; ++j) {
            sincosf(-6.283185307179586f * (float)(4 * m + j) / 512.0f, &s, &c);
            ws[WS_UNP4C + 4 * t + j] = c;
            ws[WS_UNP4S + 4 * t + j] = s;
        }
    }
    for (int i = t; i < 2560; i += 256) ws[WS_ACC + i] = 0.0f;  // zero accumulators
    // sparse mel compaction
    __shared__ int sh_k0[3][NMEL], sh_k1[3][NMEL];
    __shared__ int sh_K0[NMEL], sh_LEN[NMEL];
    if (t < 240) {
        int m = t % NMEL, r = t / NMEL;
        int kb = r * 86, ke = (kb + 86 < NBINS) ? (kb + 86) : NBINS;
        int k0 = -1, k1 = -1;
        for (int k = kb; k < ke; ++k) {
            if (fil[k * NMEL + m] > 0.0f) { if (k0 < 0) k0 = k; k1 = k; }
        }
        sh_k0[r][m] = k0; sh_k1[r][m] = k1;
    }
    __syncthreads();
    if (t < NMEL) {
        int k0 = -1, k1 = -1;
        for (int r = 0; r < 3; ++r) {
            int a = sh_k0[r][t], b1 = sh_k1[r][t];
            if (a >= 0) { if (k0 < 0) k0 = a; k1 = b1; }
        }
        int len = (k0 < 0) ? 0 : (k1 - k0 + 1);
        if (len > 32) len = 32;
        if (k0 < 0) k0 = 0;
        ((int*)ws)[WS_K0 + t] = k0;
        ((int*)ws)[WS_LEN + t] = len;
        sh_K0[t] = k0; sh_LEN[t] = len;
    }
    __syncthreads();
    for (int idx = t; idx < 32 * NMEL; idx += 256) {
        int j = idx / NMEL, m = idx - j * NMEL;
        ws[WS_WGT + idx] = (j < sh_LEN[m]) ? fil[(sh_K0[m] + j) * NMEL + m] : 0.0f;
    }
}

// ---------------- Kernel 1: 2 frames per wave (ILP), 16 frames/block + fused stats ----------------
__global__ __launch_bounds__(512, 6) void frame_logmel_kernel(
    const float* __restrict__ wav,
    const float* __restrict__ win,
    float* __restrict__ ws,
    float* __restrict__ mel_out,
    int partMode)
{
    __shared__ float s_t256c[256], s_t256s[256];
    __shared__ float s_t64c[32], s_t64s[32];
    __shared__ float4 s_upc[64], s_ups[64];
    __shared__ float s_wgt[32 * NMEL];
    __shared__ int s_k0[NMEL], s_len[NMEL];
    __shared__ float2 s_win2[200];
    __shared__ float s_spec[FRB][296];
    __shared__ float s_ss[FRB][NMEL], s_ss2[FRB][NMEL];

    const int t = threadIdx.x;
    if (t < 256) {
        s_t256c[t] = ws[WS_TW256C + t];
        s_t256s[t] = ws[WS_TW256S + t];
    }
    if (t < 32) { s_t64c[t] = ws[WS_TW64C + t]; s_t64s[t] = ws[WS_TW64S + t]; }
    if (t < 64) {
        s_upc[t] = ((const float4*)(ws + WS_UNP4C))[t];
        s_ups[t] = ((const float4*)(ws + WS_UNP4S))[t];
    }
    for (int i = t; i < 32 * NMEL; i += 512) s_wgt[i] = ws[WS_WGT + i];
    if (t < NMEL) { s_k0[t] = ((const int*)ws)[WS_K0 + t]; s_len[t] = ((const int*)ws)[WS_LEN + t]; }
    if (t < 200) s_win2[t] = ((const float2*)win)[t];
    __syncthreads();  // tables ready

    const int l = t & 63, w = t >> 6;
    const int bid = blockIdx.x;
    const int b = bid / BPB, blk = bid - b * BPB;
    int fidx[2];
    bool live[2];
    const float2* src[2];
    #pragma unroll
    for (int ff = 0; ff < 2; ++ff) {
        fidx[ff] = blk * FRB + w * 2 + ff;
        live[ff] = (fidx[ff] < F);
        src[ff] = (const float2*)(wav + (size_t)b * T + (size_t)(live[ff] ? fidx[ff] : 0) * 160);
    }

    // load frames (complex-packed pairs), per-wave means (interleaved)
    float xr[2][4], xi[2][4];
    float sum[2] = {0.0f, 0.0f};
    #pragma unroll
    for (int ff = 0; ff < 2; ++ff) {
        #pragma unroll
        for (int j = 0; j < 4; ++j) {
            int p = 64 * j + l;
            float2 v = (live[ff] && p < 200) ? src[ff][p] : make_float2(0.0f, 0.0f);
            xr[ff][j] = v.x * 32768.0f;
            xi[ff][j] = v.y * 32768.0f;
            sum[ff] += xr[ff][j] + xi[ff][j];
        }
    }
    #pragma unroll
    for (int m = 32; m >= 1; m >>= 1) {
        sum[0] += __shfl_xor(sum[0], m);
        sum[1] += __shfl_xor(sum[1], m);
    }
    float mean[2] = {sum[0] * (1.0f / 400.0f), sum[1] * (1.0f / 400.0f)};

    // preemphasis + window
    float ur[2][4], ui[2][4];
    #pragma unroll
    for (int ff = 0; ff < 2; ++ff) {
        float zr[4], zi[4];
        float carry = 0.0f;
        #pragma unroll
        for (int j = 0; j < 4; ++j) {
            float y = xi[ff][j], x0 = xr[ff][j];
            float up = __shfl(y, (l + 63) & 63);
            float nc = __shfl(y, 63);
            if (l == 0) up = (j == 0) ? x0 : carry;
            carry = nc;
            int p = 64 * j + l;
            float2 w2 = (p < 200) ? s_win2[p] : make_float2(0.0f, 0.0f);
            zr[j] = (x0 - 0.97f * up - 0.03f * mean[ff]) * w2.x;
            zi[j] = (y - 0.97f * x0 - 0.03f * mean[ff]) * w2.y;
        }
        // in-lane radix-4 first stage
        float Ar = zr[0] + zr[2], Ai = zi[0] + zi[2];
        float Br = zr[0] - zr[2], Bi = zi[0] - zi[2];
        float Cr = zr[1] + zr[3], Ci = zi[1] + zi[3];
        float Dr = zr[1] - zr[3], Di = zi[1] - zi[3];
        ur[ff][0] = Ar + Cr; ui[ff][0] = Ai + Ci;
        ur[ff][1] = Br + Di; ui[ff][1] = Bi - Dr;
        ur[ff][2] = Ar - Cr; ui[ff][2] = Ai - Ci;
        ur[ff][3] = Br - Di; ui[ff][3] = Bi + Dr;
    }
    // W_256^{j*l} twiddles (both frames interleaved)
    {
        float w1r = s_t256c[l],     w1i = s_t256s[l];
        float w2r = s_t256c[2 * l], w2i = s_t256s[2 * l];
        float w3r = s_t256c[3 * l], w3i = s_t256s[3 * l];
        #pragma unroll
        for (int ff = 0; ff < 2; ++ff) {
            float tr;
            tr = ur[ff][1] * w1r - ui[ff][1] * w1i; ui[ff][1] = ur[ff][1] * w1i + ui[ff][1] * w1r; ur[ff][1] = tr;
            tr = ur[ff][2] * w2r - ui[ff][2] * w2i; ui[ff][2] = ur[ff][2] * w2i + ui[ff][2] * w2r; ur[ff][2] = tr;
            tr = ur[ff][3] * w3r - ui[ff][3] * w3i; ui[ff][3] = ur[ff][3] * w3i + ui[ff][3] * w3r; ur[ff][3] = tr;
        }
    }

    // 64-pt FFT across lanes, 2 frames x 4 values interleaved (8-way ILP)
    #pragma unroll
    for (int h = 32; h >= 1; h >>= 1) {
        int idx = (l & (h - 1)) * (32 / h);
        bool hi = (l & h) != 0;
        float wr = hi ? s_t64c[idx] : 1.0f;
        float wi = hi ? s_t64s[idx] : 0.0f;
        float sg = hi ? -1.0f : 1.0f;
        #pragma unroll
        for (int ff = 0; ff < 2; ++ff) {
            #pragma unroll
            for (int v = 0; v < 4; ++v) {
                float pr = __shfl_xor(ur[ff][v], h), pi = __shfl_xor(ui[ff][v], h);
                float sr = fmaf(sg, ur[ff][v], pr), si = fmaf(sg, ui[ff][v], pi);
                ur[ff][v] = sr * wr - si * wi;
                ui[ff][v] = sr * wi + si * wr;
            }
        }
    }

    // real-FFT unpack in-register, power spectrum (per frame)
    const int m = brev6(l);
    const int l0 = brev6((64 - m) & 63);
    const float4 wc = s_upc[l], wn = s_ups[l];
    #pragma unroll
    for (int ff = 0; ff < 2; ++ff) {
        float b1r = __shfl_xor(ur[ff][3], 63), b1i = __shfl_xor(ui[ff][3], 63);
        float b2r = __shfl_xor(ur[ff][2], 63), b2i = __shfl_xor(ui[ff][2], 63);
        float b3r = __shfl_xor(ur[ff][1], 63), b3i = __shfl_xor(ui[ff][1], 63);
        float b0r = __shfl(ur[ff][0], l0), b0i = __shfl(ui[ff][0], l0);
        float sp[4];
        #define UNP(J, ar, ai, br, bi, twr, twi)                        \
        {                                                               \
            float Er = 0.5f * (ar + br), Ei = 0.5f * (ai - bi);         \
            float Or = 0.5f * (ai + bi), Oi = 0.5f * (br - ar);         \
            float Xr = Er + twr * Or - twi * Oi;                        \
            float Xi = Ei + twr * Oi + twi * Or;                        \
            sp[J] = Xr * Xr + Xi * Xi;                                  \
        }
        UNP(0, ur[ff][0], ui[ff][0], b0r, b0i, wc.x, wn.x)
        UNP(1, ur[ff][1], ui[ff][1], b1r, b1i, wc.y, wn.y)
        UNP(2, ur[ff][2], ui[ff][2], b2r, b2i, wc.z, wn.z)
        UNP(3, ur[ff][3], ui[ff][3], b3r, b3i, wc.w, wn.w)
        #undef UNP
        ((float4*)s_spec[w * 2 + ff])[m + (m >> 3)] = make_float4(sp[0], sp[1], sp[2], sp[3]);
        if (l == 0) {
            float d = ur[ff][0] - ui[ff][0];  // X[256] = Re(Z0) - Im(Z0)
            s_spec[w * 2 + ff][specIdx(256)] = d * d;
        }
    }

    // sparse mel projection (wave-private spec; no barrier needed)
    const int q = l & 3;
    #pragma unroll
    for (int ff = 0; ff < 2; ++ff) {
        const int fr = w * 2 + ff;
        const size_t outbase = (size_t)(b * F + fidx[ff]) * NMEL;
        // narrow mels 0..63: one lane per mel
        float mv0;
        {
            int mel = l;
            int k0 = s_k0[mel], len = s_len[mel];
            float acc = 0.0f;
            for (int i = 0; i < len; ++i)
                acc = fmaf(s_spec[fr][specIdx(k0 + i)], s_wgt[i * NMEL + mel], acc);
            mv0 = __logf(fmaxf(acc, MEL_FLOOR));
            if (live[ff]) mel_out[outbase + l] = mv0;
        }
        // wide mels 64..79: 4 lanes per mel, shfl-combine
        float mv1 = 0.0f;
        {
            int mel = 64 + (l >> 2);
            int k0 = s_k0[mel], len = s_len[mel];
            float acc = 0.0f;
            for (int i = q; i < len; i += 4)
                acc = fmaf(s_spec[fr][specIdx(k0 + i)], s_wgt[i * NMEL + mel], acc);
            acc += __shfl_xor(acc, 1);
            acc += __shfl_xor(acc, 2);
            if (q == 0) {
                mv1 = __logf(fmaxf(acc, MEL_FLOOR));
                if (live[ff]) mel_out[outbase + mel] = mv1;
            }
        }
        // stats partial stage
        float v0 = live[ff] ? mv0 : 0.0f;
        s_ss[fr][l] = v0;
        s_ss2[fr][l] = v0 * v0;
        if (q == 0) {
            float v1 = live[ff] ? mv1 : 0.0f;
            s_ss[fr][64 + (l >> 2)] = v1;
            s_ss2[fr][64 + (l >> 2)] = v1 * v1;
        }
    }
    __syncthreads();
    if (t < 160) {
        const int mel = (t < 80) ? t : (t - 80);
        float s = 0.0f;
        if (t < 80) {
            #pragma unroll
            for (int i = 0; i < FRB; ++i) s += s_ss[i][mel];
        } else {
            #pragma unroll
            for (int i = 0; i < FRB; ++i) s += s_ss2[i][mel];
        }
        if (partMode)
            ws[WS_PART + (size_t)bid * 160 + t] = s;
        else
            atomicAdd(&ws[WS_ACC + b * 160 + t], s);
    }
}

// ---------------- Kernel 2: finalize stats (parallel over 8 rows) ----------------
__global__ __launch_bounds__(640) void stats_final_kernel(float* __restrict__ ws, int partMode)
{
    const int b = blockIdx.x;
    const int m = threadIdx.x;   // 0..79
    const int r = threadIdx.y;   // 0..7
    __shared__ float shs[8][NMEL], shs2[8][NMEL];
    float s = 0.0f, s2 = 0.0f;
    if (partMode) {
        for (int c = r; c < BPB; c += 8) {
            const float* base = ws + WS_PART + (size_t)(b * BPB + c) * 160;
            s += base[m];
            s2 += base[80 + m];
        }
    }
    shs[r][m] = s; shs2[r][m] = s2;
    __syncthreads();
    if (r == 0) {
        double ds = 0.0, ds2 = 0.0;
        if (partMode) {
            #pragma unroll
            for (int i = 0; i < 8; ++i) { ds += (double)shs[i][m]; ds2 += (double)shs2[i][m]; }
        } else {
            ds = (double)ws[WS_ACC + b * 160 + m];
            ds2 = (double)ws[WS_ACC + b * 160 + 80 + m];
        }
        double mean = ds / (double)F;
        double var = (ds2 - ds * ds / (double)F) / (double)(F - 1);
        ws[WS_STAT + b * 160 + m] = (float)mean;
        ws[WS_STAT + b * 160 + 80 + m] = (float)(1.0 / sqrt(var + 1e-7));
    }
}

// ---------------- Kernel 3: normalize (float4) + mask ----------------
__global__ __launch_bounds__(256) void norm_mask_kernel(
    float* __restrict__ out, const float* __restrict__ ws)
{
    const float* stat = ws + WS_STAT;
    const int total4 = (B * F * NMEL) / 4;
    const int stride = gridDim.x * blockDim.x;
    float4* out4 = (float4*)out;
    for (int e4 = blockIdx.x * blockDim.x + threadIdx.x; e4 < total4; e4 += stride) {
        int e = e4 * 4;
        int b = e / (F * NMEL);
        int m = e % NMEL;
        const float* sb = stat + b * 160;
        float4 v = out4[e4];
        v.x = (v.x - sb[m + 0]) * sb[80 + m + 0];
        v.y = (v.y - sb[m + 1]) * sb[80 + m + 1];
        v.z = (v.z - sb[m + 2]) * sb[80 + m + 2];
        v.w = (v.w - sb[m + 3]) * sb[80 + m + 3];
        out4[e4] = v;
    }
    const int nmask = B * (F / 2);
    float* mask = out + (size_t)B * F * NMEL;
    for (int e = blockIdx.x * blockDim.x + threadIdx.x; e < nmask; e += stride)
        mask[e] = 1.0f;
}

extern "C" void kernel_launch(void* const* d_in, const int* in_sizes, int n_in,
                              void* d_out, int out_size, void* d_ws, size_t ws_size,
                              hipStream_t stream) {
    const float* wav = (const float*)d_in[0];
    const float* fil = (const float*)d_in[1];
    const float* win = (const float*)d_in[2];
    float* out = (float*)d_out;
    float* ws = (float*)d_ws;

    const int partMode = (ws_size >= WS_NEED_PART) ? 1 : 0;

    setup_kernel<<<1, 256, 0, stream>>>(fil, ws);
    frame_logmel_kernel<<<NBLK, 512, 0, stream>>>(wav, win, ws, out, partMode);
    stats_final_kernel<<<B, dim3(NMEL, 8), 0, stream>>>(ws, partMode);
    norm_mask_kernel<<<2048, 256, 0, stream>>>(out, ws);
}